// Round 2
// baseline (571.749 us; speedup 1.0000x reference)
//
#include <hip/hip_runtime.h>

// T=512, B=512, K=8, V=5, H=30, NL=4, NLAB=3
#define TT 512
#define BB 512
#define KK 8
#define HH 30
#define GG 120   // 4*H
#define NLAYER 4

__device__ __forceinline__ float rcp_f(float x) { return __builtin_amdgcn_rcpf(x); }

// forced VOP3P packed f32 math (compiler won't form these on its own)
__device__ __forceinline__ float2 pk_fma(float2 a, float2 b, float2 c) {
    float2 d;
    asm("v_pk_fma_f32 %0, %1, %2, %3" : "=v"(d) : "v"(a), "v"(b), "v"(c));
    return d;
}
__device__ __forceinline__ float2 pk_add(float2 a, float2 b) {
    float2 d;
    asm("v_pk_add_f32 %0, %1, %2" : "=v"(d) : "v"(a), "v"(b));
    return d;
}

// One block = one sample. 4 waves = 4 LSTM layers, pipelined over time
// (wave l handles t = s - l at block-step s). Pooled embeddings are
// precomputed per 16-step chunk by ALL threads at chunk boundaries
// (seqring), so every wave's step is symmetric: 16 ds_read_b128 +
// 60 v_pk_fma_f32 + activations. x/w global prefetch is held in registers
// for one chunk before the LDS commit so vmcnt never stalls the chain.
__global__ __launch_bounds__(256, 2) void rnn_fused(
    const int*   __restrict__ xin,  const float* __restrict__ wxin,
    const float* __restrict__ embed,
    const float* __restrict__ Wih,  const float* __restrict__ Whh,
    const float* __restrict__ bih,  const float* __restrict__ bhh,
    const float* __restrict__ W1,   const float* __restrict__ b1,
    const float* __restrict__ W2,   const float* __restrict__ b2,
    const float* __restrict__ fcW,  const float* __restrict__ fcb,
    float* __restrict__ out)
{
    __shared__ alignas(16) float hstore[TT * HH];        // layer-3 h, 61440 B
    __shared__ alignas(16) float seqring[2][16][32];     // pooled-embed chunks
    __shared__ alignas(16) int   ringx[4][16][KK];       // x stream ring
    __shared__ alignas(16) float ringw[4][16][KK];       // wx stream ring
    __shared__ alignas(16) float hbuf[NLAYER][2][32];    // h handoff (dbuf)
    __shared__ alignas(16) float re_s[5 * HH];           // relu(embed)
    __shared__ alignas(16) float energy_s[TT];
    __shared__ float red_s[16];
    __shared__ float part_s[8][HH];
    __shared__ float pooled_s[HH];
    __shared__ float logits_s[3];

    const int tid  = threadIdx.x;
    const int wv   = tid >> 6;
    const int lane = tid & 63;
    const int b    = blockIdx.x;

    // ---- preamble ----
    ((float*)hbuf)[tid] = 0.0f;                          // 256 floats exactly
    if (tid < 5 * HH) re_s[tid] = fmaxf(embed[tid], 0.0f);

    int4   hx; float4 hw;                                // held x/w regs (wave 0, lanes<32)
    if (wv == 0 && lane < 32) {
        const int r = lane >> 1, hf = lane & 1;
        // chunk 0,1 -> LDS directly; chunk 2 -> held registers
        #pragma unroll
        for (int cc = 0; cc < 2; ++cc) {
            long off = ((long)(16 * cc + r) * BB + b) * KK + hf * 4;
            *(int4*)(&ringx[cc][r][hf * 4])   = *(const int4*)(xin  + off);
            *(float4*)(&ringw[cc][r][hf * 4]) = *(const float4*)(wxin + off);
        }
        long off2 = ((long)(32 + r) * BB + b) * KK + hf * 4;
        hx = *(const int4*)(xin  + off2);
        hw = *(const float4*)(wxin + off2);
    }

    // ---- per-lane weights (packed float2; rows are 120B -> 8B aligned) ----
    const int p  = (lane < 60) ? lane : 59;
    const int g0 = p, g1 = p + 60;   // lanes<30: (i,g); lanes 30-59: (f,o)
    float2 wih0p[15], wih1p[15], whh0p[15], whh1p[15];
    {
        const float* WihL = Wih + wv * GG * HH;
        const float* WhhL = Whh + wv * GG * HH;
        #pragma unroll
        for (int kk = 0; kk < 15; ++kk) {
            wih0p[kk] = *(const float2*)(WihL + g0 * HH + 2 * kk);
            wih1p[kk] = *(const float2*)(WihL + g1 * HH + 2 * kk);
            whh0p[kk] = *(const float2*)(WhhL + g0 * HH + 2 * kk);
            whh1p[kk] = *(const float2*)(WhhL + g1 * HH + 2 * kk);
        }
    }
    const float bias0 = bih[wv * GG + g0] + bhh[wv * GG + g0];
    const float bias1 = bih[wv * GG + g1] + bhh[wv * GG + g1];
    // unified activation for gate B: tanh(x)=2*sig(2x)-1 (lanes<30), else sig(x)
    const float mBneg = (lane < HH) ? -2.0f : -1.0f;
    const float aB    = (lane < HH) ?  2.0f :  1.0f;
    const float dB    = (lane < HH) ? -1.0f :  0.0f;

    __syncthreads();

    // ---- seq chunk 0 (all threads) ----
    {
        #pragma unroll
        for (int oo = 0; oo < 2; ++oo) {
            const int o = tid + oo * 256;
            if (o < 480) {
                const int tr = o / HH, j = o - tr * HH;
                int4   xa = *(const int4*)(&ringx[0][tr][0]);
                int4   xb = *(const int4*)(&ringx[0][tr][4]);
                float4 wa = *(const float4*)(&ringw[0][tr][0]);
                float4 wb = *(const float4*)(&ringw[0][tr][4]);
                float acc = re_s[xa.x * HH + j] * wa.x;
                acc = fmaf(re_s[xa.y * HH + j], wa.y, acc);
                acc = fmaf(re_s[xa.z * HH + j], wa.z, acc);
                acc = fmaf(re_s[xa.w * HH + j], wa.w, acc);
                acc = fmaf(re_s[xb.x * HH + j], wb.x, acc);
                acc = fmaf(re_s[xb.y * HH + j], wb.y, acc);
                acc = fmaf(re_s[xb.z * HH + j], wb.z, acc);
                acc = fmaf(re_s[xb.w * HH + j], wb.w, acc);
                seqring[0][tr][j] = acc * 0.125f;
            }
        }
    }
    __syncthreads();

    float c_val = 0.0f;

    // ---- pipelined recurrence: 515 block-steps ----
    for (int s = 0; s < TT + NLAYER - 1; ++s) {
        // chunk-boundary work (block-uniform branch)
        if ((s & 15) == 0) {
            const int c = s >> 4;
            if (wv == 0 && lane < 32) {
                const int r = lane >> 1, hf = lane & 1;
                if (c + 2 <= 31) {   // commit held regs (chunk c+2) to ring
                    const int sl = (c + 2) & 3;
                    *(int4*)(&ringx[sl][r][hf * 4])   = hx;
                    *(float4*)(&ringw[sl][r][hf * 4]) = hw;
                }
                if (c + 3 <= 31) {   // start load of chunk c+3 into regs
                    long off = ((long)(16 * (c + 3) + r) * BB + b) * KK + hf * 4;
                    hx = *(const int4*)(xin  + off);
                    hw = *(const float4*)(wxin + off);
                }
            }
            if (c + 1 <= 31) {       // all threads: seq for chunk c+1
                const int sl = (c + 1) & 3, par = (c + 1) & 1;
                #pragma unroll
                for (int oo = 0; oo < 2; ++oo) {
                    const int o = tid + oo * 256;
                    if (o < 480) {
                        const int tr = o / HH, j = o - tr * HH;
                        int4   xa = *(const int4*)(&ringx[sl][tr][0]);
                        int4   xb = *(const int4*)(&ringx[sl][tr][4]);
                        float4 wa = *(const float4*)(&ringw[sl][tr][0]);
                        float4 wb = *(const float4*)(&ringw[sl][tr][4]);
                        float acc = re_s[xa.x * HH + j] * wa.x;
                        acc = fmaf(re_s[xa.y * HH + j], wa.y, acc);
                        acc = fmaf(re_s[xa.z * HH + j], wa.z, acc);
                        acc = fmaf(re_s[xa.w * HH + j], wa.w, acc);
                        acc = fmaf(re_s[xb.x * HH + j], wb.x, acc);
                        acc = fmaf(re_s[xb.y * HH + j], wb.y, acc);
                        acc = fmaf(re_s[xb.z * HH + j], wb.z, acc);
                        acc = fmaf(re_s[xb.w * HH + j], wb.w, acc);
                        seqring[par][tr][j] = acc * 0.125f;
                    }
                }
            }
        }

        const int t = s - wv;                       // wave-uniform
        if (t >= 0 && t < TT) {
            const float* xsrc = (wv == 0) ? &seqring[(s >> 4) & 1][s & 15][0]
                                          : &hbuf[wv - 1][(s - 1) & 1][0];
            const float* hsrc = &hbuf[wv][(s - 1) & 1][0];
            float4 X[8], Hq[8];
            {
                const float4* xv = (const float4*)xsrc;
                const float4* hv = (const float4*)hsrc;
                #pragma unroll
                for (int q = 0; q < 8; ++q) X[q]  = xv[q];
                #pragma unroll
                for (int q = 0; q < 8; ++q) Hq[q] = hv[q];
            }
            float2 acc0a = {0.f, 0.f}, acc0b = {0.f, 0.f};
            float2 acc1a = {0.f, 0.f}, acc1b = {0.f, 0.f};
            #pragma unroll
            for (int pp = 0; pp < 15; ++pp) {
                const float4 v = X[pp >> 1];
                const float2 xp = (pp & 1) ? make_float2(v.z, v.w)
                                           : make_float2(v.x, v.y);
                if (pp & 1) { acc0b = pk_fma(wih0p[pp], xp, acc0b);
                              acc1b = pk_fma(wih1p[pp], xp, acc1b); }
                else        { acc0a = pk_fma(wih0p[pp], xp, acc0a);
                              acc1a = pk_fma(wih1p[pp], xp, acc1a); }
            }
            #pragma unroll
            for (int pp = 0; pp < 15; ++pp) {
                const float4 v = Hq[pp >> 1];
                const float2 hp = (pp & 1) ? make_float2(v.z, v.w)
                                           : make_float2(v.x, v.y);
                if (pp & 1) { acc0b = pk_fma(whh0p[pp], hp, acc0b);
                              acc1b = pk_fma(whh1p[pp], hp, acc1b); }
                else        { acc0a = pk_fma(whh0p[pp], hp, acc0a);
                              acc1a = pk_fma(whh1p[pp], hp, acc1a); }
            }
            const float2 s0 = pk_add(acc0a, acc0b);
            const float2 s1 = pk_add(acc1a, acc1b);
            const float gA = s0.x + s0.y + bias0;   // i (lanes<30) / f
            const float gB = s1.x + s1.y + bias1;   // g (lanes<30) / o

            const float actA = rcp_f(1.0f + __expf(-gA));          // sigmoid
            const float sB   = rcp_f(1.0f + __expf(gB * mBneg));
            const float actB = fmaf(aB, sB, dB);                   // tanh | sigmoid

            const float fI = __shfl(actA, lane + HH, 64);
            const float oI = __shfl(actB, lane + HH, 64);
            c_val = fmaf(fI, c_val, actA * actB);                  // garbage lanes>=30, unused
            const float tC = fmaf(2.0f, rcp_f(1.0f + __expf(-2.0f * c_val)), -1.0f);
            const float hv = oI * tC;
            if (lane < HH) {
                hbuf[wv][s & 1][lane] = hv;
                if (wv == NLAYER - 1) hstore[t * HH + lane] = hv;
            }
        }
        __syncthreads();
    }

    // ---- attention: energy_t = relu(h_t @ W1 + b1) @ W2 + b2 ----
    {
        float w1cx[15], w1cy[15];
        #pragma unroll
        for (int k = 0; k < 15; ++k) {
            w1cx[k] = W1[(2 * k) * 64 + lane];
            w1cy[k] = W1[(2 * k + 1) * 64 + lane];
        }
        const float b1v = b1[lane];
        const float w2v = W2[lane];
        const float b2v = b2[0];
        for (int t = wv; t < TT; t += 4) {
            const float* hrow = hstore + t * HH;
            float ax = b1v, ay = 0.0f;
            #pragma unroll
            for (int k = 0; k < 15; ++k) {
                float2 h2 = *(const float2*)(hrow + 2 * k);
                ax = fmaf(w1cx[k], h2.x, ax);
                ay = fmaf(w1cy[k], h2.y, ay);
            }
            float e = fmaxf(ax + ay, 0.0f) * w2v;
            #pragma unroll
            for (int m = 1; m < 64; m <<= 1) e += __shfl_xor(e, m, 64);
            if (lane == 0) energy_s[t] = e + b2v;
        }
    }
    __syncthreads();

    // ---- softmax over T ----
    float mx = -3.0e38f;
    for (int i = tid; i < TT; i += 256) mx = fmaxf(mx, energy_s[i]);
    #pragma unroll
    for (int m = 1; m < 64; m <<= 1) mx = fmaxf(mx, __shfl_xor(mx, m, 64));
    if (lane == 0) red_s[wv] = mx;
    __syncthreads();
    mx = fmaxf(fmaxf(red_s[0], red_s[1]), fmaxf(red_s[2], red_s[3]));
    float ssum = 0.0f;
    for (int i = tid; i < TT; i += 256) {
        float ev = __expf(energy_s[i] - mx);
        energy_s[i] = ev;
        ssum += ev;
    }
    #pragma unroll
    for (int m = 1; m < 64; m <<= 1) ssum += __shfl_xor(ssum, m, 64);
    if (lane == 0) red_s[8 + wv] = ssum;
    __syncthreads();
    const float invS = rcp_f(red_s[8] + red_s[9] + red_s[10] + red_s[11]);

    // ---- pooled_j = sum_t softmax_t * h[t][j] ----
    {
        const int g = tid >> 5, jj = tid & 31;
        if (jj < HH) {
            float part = 0.0f;
            for (int t = g; t < TT; t += 8)
                part = fmaf(energy_s[t] * invS, hstore[t * HH + jj], part);
            part_s[g][jj] = part;
        }
    }
    __syncthreads();
    if (tid < HH) {
        float pv = 0.0f;
        #pragma unroll
        for (int q = 0; q < 8; ++q) pv += part_s[q][tid];
        pooled_s[tid] = pv;
    }
    __syncthreads();

    // ---- FC (30->3) + softmax ----
    if (tid < 3) {
        float acc = fcb[tid];
        #pragma unroll
        for (int k = 0; k < HH; ++k) acc = fmaf(pooled_s[k], fcW[k * 3 + tid], acc);
        logits_s[tid] = acc;
    }
    __syncthreads();
    if (tid == 0) {
        float l0 = logits_s[0], l1 = logits_s[1], l2 = logits_s[2];
        float m3 = fmaxf(l0, fmaxf(l1, l2));
        float e0 = __expf(l0 - m3), e1 = __expf(l1 - m3), e2 = __expf(l2 - m3);
        float inv = rcp_f(e0 + e1 + e2);
        out[b * 3 + 0] = e0 * inv; out[b * 3 + 1] = e1 * inv; out[b * 3 + 2] = e2 * inv;
    }
}

extern "C" void kernel_launch(void* const* d_in, const int* in_sizes, int n_in,
                              void* d_out, int out_size, void* d_ws, size_t ws_size,
                              hipStream_t stream)
{
    (void)in_sizes; (void)n_in; (void)d_ws; (void)ws_size; (void)out_size;
    rnn_fused<<<BB, 256, 0, stream>>>(
        (const int*)  d_in[0],  (const float*)d_in[1],  (const float*)d_in[2],
        (const float*)d_in[3],  (const float*)d_in[4],  (const float*)d_in[5],
        (const float*)d_in[6],  (const float*)d_in[7],  (const float*)d_in[8],
        (const float*)d_in[9],  (const float*)d_in[10], (const float*)d_in[11],
        (const float*)d_in[12], (float*)d_out);
}

// Round 3
// 532.042 us; speedup vs baseline: 1.0746x; 1.0746x over previous
//
#include <hip/hip_runtime.h>

// T=512, B=512, K=8, V=5, H=30, NL=4, NLAB=3
#define TT 512
#define BB 512
#define KK 8
#define HH 30
#define GG 120   // 4*H
#define NLAYER 4

__device__ __forceinline__ float rcp_f(float x) { return __builtin_amdgcn_rcpf(x); }

// broadcast lane k of v to all lanes (VALU, no LDS pipe)
__device__ __forceinline__ float rdlane_f(float v, int l) {
    return __int_as_float(__builtin_amdgcn_readlane(__float_as_int(v), l));
}
// packed f32 FMA with the broadcast operand in an SGPR pair (1 scalar src allowed)
__device__ __forceinline__ float2 pk_fma_s(float2 a, float2 bs, float2 c) {
    float2 d;
    asm("v_pk_fma_f32 %0, %1, %2, %3" : "=v"(d) : "v"(a), "s"(bs), "v"(c));
    return d;
}
__device__ __forceinline__ float2 pk_add(float2 a, float2 b) {
    float2 d;
    asm("v_pk_add_f32 %0, %1, %2" : "=v"(d) : "v"(a), "v"(b));
    return d;
}

// One block = one sample. 4 waves = 4 LSTM layers pipelined over time
// (wave l handles t = s - l at block-step s).
// Broadcast operands (x_t, h_{t-1}) are distributed to lanes via v_readlane
// -> SGPR pairs feeding v_pk_fma_f32, NOT via per-lane LDS b128 reads: the
// per-CU DS pipe was the R2 bottleneck (128 ds_read_b128/CU/step ~ 1536 cyc).
// Per-step LDS is now 1 ds_read_b32 + 1 ds_write_b32 + 2 bpermute per wave.
__global__ __launch_bounds__(256, 2) void rnn_fused(
    const int*   __restrict__ xin,  const float* __restrict__ wxin,
    const float* __restrict__ embed,
    const float* __restrict__ Wih,  const float* __restrict__ Whh,
    const float* __restrict__ bih,  const float* __restrict__ bhh,
    const float* __restrict__ W1,   const float* __restrict__ b1,
    const float* __restrict__ W2,   const float* __restrict__ b2,
    const float* __restrict__ fcW,  const float* __restrict__ fcb,
    float* __restrict__ out)
{
    __shared__ alignas(16) float hstore[TT * HH];        // layer-3 h, 61440 B
    __shared__ alignas(16) float seqring[2][16][32];     // pooled-embed chunks
    __shared__ alignas(16) int   ringx[4][16][KK];       // x stream ring
    __shared__ alignas(16) float ringw[4][16][KK];       // wx stream ring
    __shared__ alignas(16) float hbuf[NLAYER][2][32];    // h handoff (dbuf)
    __shared__ alignas(16) float re_s[5 * HH];           // relu(embed)
    __shared__ alignas(16) float energy_s[TT];
    __shared__ float red_s[16];
    __shared__ float part_s[8][HH];
    __shared__ float pooled_s[HH];
    __shared__ float logits_s[3];

    const int tid  = threadIdx.x;
    const int wv   = tid >> 6;
    const int lane = tid & 63;
    const int b    = blockIdx.x;

    // ---- preamble ----
    ((float*)hbuf)[tid] = 0.0f;                          // 256 floats exactly
    if (tid < 5 * HH) re_s[tid] = fmaxf(embed[tid], 0.0f);

    int4   hx; float4 hw;                                // held x/w regs (wave 0, lanes<32)
    if (wv == 0 && lane < 32) {
        const int r = lane >> 1, hf = lane & 1;
        #pragma unroll
        for (int cc = 0; cc < 2; ++cc) {                 // chunks 0,1 -> LDS
            long off = ((long)(16 * cc + r) * BB + b) * KK + hf * 4;
            *(int4*)(&ringx[cc][r][hf * 4])   = *(const int4*)(xin  + off);
            *(float4*)(&ringw[cc][r][hf * 4]) = *(const float4*)(wxin + off);
        }
        long off2 = ((long)(32 + r) * BB + b) * KK + hf * 4;  // chunk 2 -> regs
        hx = *(const int4*)(xin  + off2);
        hw = *(const float4*)(wxin + off2);
    }

    // ---- per-lane weights (packed float2; rows are 120B -> 8B aligned) ----
    const int p  = (lane < 60) ? lane : 59;
    const int g0 = p, g1 = p + 60;   // lanes<30: (i,g); lanes 30-59: (f,o)
    float2 wih0p[15], wih1p[15], whh0p[15], whh1p[15];
    {
        const float* WihL = Wih + wv * GG * HH;
        const float* WhhL = Whh + wv * GG * HH;
        #pragma unroll
        for (int kk = 0; kk < 15; ++kk) {
            wih0p[kk] = *(const float2*)(WihL + g0 * HH + 2 * kk);
            wih1p[kk] = *(const float2*)(WihL + g1 * HH + 2 * kk);
            whh0p[kk] = *(const float2*)(WhhL + g0 * HH + 2 * kk);
            whh1p[kk] = *(const float2*)(WhhL + g1 * HH + 2 * kk);
        }
    }
    const float bias0 = bih[wv * GG + g0] + bhh[wv * GG + g0];
    const float bias1 = bih[wv * GG + g1] + bhh[wv * GG + g1];
    // unified activation for gate B: tanh(x)=2*sig(2x)-1 (lanes<30), else sig(x)
    const float mBneg = (lane < HH) ? -2.0f : -1.0f;
    const float aB    = (lane < HH) ?  2.0f :  1.0f;
    const float dB    = (lane < HH) ? -1.0f :  0.0f;

    __syncthreads();

    // ---- seq chunk 0 (all threads) ----
    #pragma unroll
    for (int oo = 0; oo < 2; ++oo) {
        const int o = tid + oo * 256;
        if (o < 480) {
            const int tr = o / HH, j = o - tr * HH;
            int4   xa = *(const int4*)(&ringx[0][tr][0]);
            int4   xb = *(const int4*)(&ringx[0][tr][4]);
            float4 wa = *(const float4*)(&ringw[0][tr][0]);
            float4 wb = *(const float4*)(&ringw[0][tr][4]);
            float acc = re_s[xa.x * HH + j] * wa.x;
            acc = fmaf(re_s[xa.y * HH + j], wa.y, acc);
            acc = fmaf(re_s[xa.z * HH + j], wa.z, acc);
            acc = fmaf(re_s[xa.w * HH + j], wa.w, acc);
            acc = fmaf(re_s[xb.x * HH + j], wb.x, acc);
            acc = fmaf(re_s[xb.y * HH + j], wb.y, acc);
            acc = fmaf(re_s[xb.z * HH + j], wb.z, acc);
            acc = fmaf(re_s[xb.w * HH + j], wb.w, acc);
            seqring[0][tr][j] = acc * 0.125f;
        }
    }
    __syncthreads();

    float c_val = 0.0f;
    float hprev = 0.0f;    // lane k holds own h_{t-1}[k] (k<30)

    // ---- pipelined recurrence: 515 block-steps ----
    for (int s = 0; s < TT + NLAYER - 1; ++s) {
        if ((s & 15) == 0) {                       // chunk boundary (uniform)
            const int c = s >> 4;
            if (wv == 0 && lane < 32) {
                const int r = lane >> 1, hf = lane & 1;
                if (c + 2 <= 31) {                 // commit held regs to ring
                    const int sl = (c + 2) & 3;
                    *(int4*)(&ringx[sl][r][hf * 4])   = hx;
                    *(float4*)(&ringw[sl][r][hf * 4]) = hw;
                }
                if (c + 3 <= 31) {                 // load chunk c+3 into regs
                    long off = ((long)(16 * (c + 3) + r) * BB + b) * KK + hf * 4;
                    hx = *(const int4*)(xin  + off);
                    hw = *(const float4*)(wxin + off);
                }
            }
            if (c + 1 <= 31) {                     // all threads: seq chunk c+1
                const int sl = (c + 1) & 3, par = (c + 1) & 1;
                #pragma unroll
                for (int oo = 0; oo < 2; ++oo) {
                    const int o = tid + oo * 256;
                    if (o < 480) {
                        const int tr = o / HH, j = o - tr * HH;
                        int4   xa = *(const int4*)(&ringx[sl][tr][0]);
                        int4   xb = *(const int4*)(&ringx[sl][tr][4]);
                        float4 wa = *(const float4*)(&ringw[sl][tr][0]);
                        float4 wb = *(const float4*)(&ringw[sl][tr][4]);
                        float acc = re_s[xa.x * HH + j] * wa.x;
                        acc = fmaf(re_s[xa.y * HH + j], wa.y, acc);
                        acc = fmaf(re_s[xa.z * HH + j], wa.z, acc);
                        acc = fmaf(re_s[xa.w * HH + j], wa.w, acc);
                        acc = fmaf(re_s[xb.x * HH + j], wb.x, acc);
                        acc = fmaf(re_s[xb.y * HH + j], wb.y, acc);
                        acc = fmaf(re_s[xb.z * HH + j], wb.z, acc);
                        acc = fmaf(re_s[xb.w * HH + j], wb.w, acc);
                        seqring[par][tr][j] = acc * 0.125f;
                    }
                }
            }
        }

        const int t = s - wv;                      // wave-uniform
        if (t >= 0 && t < TT) {
            const float* xsrc = (wv == 0) ? &seqring[(s >> 4) & 1][s & 15][0]
                                          : &hbuf[wv - 1][(s - 1) & 1][0];
            const float xi = xsrc[lane & 31];      // ONE ds_read_b32; lane i holds x[i]

            // h-side (no LDS dependency — fills the ds_read latency window)
            float2 ah0 = {0.f, 0.f}, ah1 = {0.f, 0.f};
            #pragma unroll
            for (int k = 0; k < 15; ++k) {
                float2 hp;
                hp.x = rdlane_f(hprev, 2 * k);
                hp.y = rdlane_f(hprev, 2 * k + 1);
                ah0 = pk_fma_s(whh0p[k], hp, ah0);
                ah1 = pk_fma_s(whh1p[k], hp, ah1);
            }
            // x-side
            float2 ax0 = {0.f, 0.f}, ax1 = {0.f, 0.f};
            #pragma unroll
            for (int k = 0; k < 15; ++k) {
                float2 xp;
                xp.x = rdlane_f(xi, 2 * k);
                xp.y = rdlane_f(xi, 2 * k + 1);
                ax0 = pk_fma_s(wih0p[k], xp, ax0);
                ax1 = pk_fma_s(wih1p[k], xp, ax1);
            }
            const float2 s0 = pk_add(ax0, ah0);
            const float2 s1 = pk_add(ax1, ah1);
            const float gA = s0.x + s0.y + bias0;  // i (lanes<30) / f
            const float gB = s1.x + s1.y + bias1;  // g (lanes<30) / o

            const float actA = rcp_f(1.0f + __expf(-gA));       // sigmoid
            const float sB   = rcp_f(1.0f + __expf(gB * mBneg));
            const float actB = fmaf(aB, sB, dB);                // tanh | sigmoid

            const float fI = __shfl(actA, lane + HH, 64);
            const float oI = __shfl(actB, lane + HH, 64);
            c_val = fmaf(fI, c_val, actA * actB);               // lanes>=30: garbage, unused
            const float tC = fmaf(2.0f, rcp_f(1.0f + __expf(-2.0f * c_val)), -1.0f);
            const float hv = oI * tC;
            hprev = hv;                                         // lane k: h_t[k]
            if (lane < HH) {
                hbuf[wv][s & 1][lane] = hv;                     // ONE ds_write_b32
                if (wv == NLAYER - 1) hstore[t * HH + lane] = hv;
            }
        }
        __syncthreads();
    }

    // ---- attention: energy_t = relu(h_t @ W1 + b1) @ W2 + b2 ----
    {
        float w1cx[15], w1cy[15];
        #pragma unroll
        for (int k = 0; k < 15; ++k) {
            w1cx[k] = W1[(2 * k) * 64 + lane];
            w1cy[k] = W1[(2 * k + 1) * 64 + lane];
        }
        const float b1v = b1[lane];
        const float w2v = W2[lane];
        const float b2v = b2[0];
        for (int t = wv; t < TT; t += 4) {
            const float* hrow = hstore + t * HH;
            float ax = b1v, ay = 0.0f;
            #pragma unroll
            for (int k = 0; k < 15; ++k) {
                float2 h2 = *(const float2*)(hrow + 2 * k);
                ax = fmaf(w1cx[k], h2.x, ax);
                ay = fmaf(w1cy[k], h2.y, ay);
            }
            float e = fmaxf(ax + ay, 0.0f) * w2v;
            #pragma unroll
            for (int m = 1; m < 64; m <<= 1) e += __shfl_xor(e, m, 64);
            if (lane == 0) energy_s[t] = e + b2v;
        }
    }
    __syncthreads();

    // ---- softmax over T ----
    float mx = -3.0e38f;
    for (int i = tid; i < TT; i += 256) mx = fmaxf(mx, energy_s[i]);
    #pragma unroll
    for (int m = 1; m < 64; m <<= 1) mx = fmaxf(mx, __shfl_xor(mx, m, 64));
    if (lane == 0) red_s[wv] = mx;
    __syncthreads();
    mx = fmaxf(fmaxf(red_s[0], red_s[1]), fmaxf(red_s[2], red_s[3]));
    float ssum = 0.0f;
    for (int i = tid; i < TT; i += 256) {
        float ev = __expf(energy_s[i] - mx);
        energy_s[i] = ev;
        ssum += ev;
    }
    #pragma unroll
    for (int m = 1; m < 64; m <<= 1) ssum += __shfl_xor(ssum, m, 64);
    if (lane == 0) red_s[8 + wv] = ssum;
    __syncthreads();
    const float invS = rcp_f(red_s[8] + red_s[9] + red_s[10] + red_s[11]);

    // ---- pooled_j = sum_t softmax_t * h[t][j] ----
    {
        const int g = tid >> 5, jj = tid & 31;
        if (jj < HH) {
            float part = 0.0f;
            for (int t = g; t < TT; t += 8)
                part = fmaf(energy_s[t] * invS, hstore[t * HH + jj], part);
            part_s[g][jj] = part;
        }
    }
    __syncthreads();
    if (tid < HH) {
        float pv = 0.0f;
        #pragma unroll
        for (int q = 0; q < 8; ++q) pv += part_s[q][tid];
        pooled_s[tid] = pv;
    }
    __syncthreads();

    // ---- FC (30->3) + softmax ----
    if (tid < 3) {
        float acc = fcb[tid];
        #pragma unroll
        for (int k = 0; k < HH; ++k) acc = fmaf(pooled_s[k], fcW[k * 3 + tid], acc);
        logits_s[tid] = acc;
    }
    __syncthreads();
    if (tid == 0) {
        float l0 = logits_s[0], l1 = logits_s[1], l2 = logits_s[2];
        float m3 = fmaxf(l0, fmaxf(l1, l2));
        float e0 = __expf(l0 - m3), e1 = __expf(l1 - m3), e2 = __expf(l2 - m3);
        float inv = rcp_f(e0 + e1 + e2);
        out[b * 3 + 0] = e0 * inv; out[b * 3 + 1] = e1 * inv; out[b * 3 + 2] = e2 * inv;
    }
}

extern "C" void kernel_launch(void* const* d_in, const int* in_sizes, int n_in,
                              void* d_out, int out_size, void* d_ws, size_t ws_size,
                              hipStream_t stream)
{
    (void)in_sizes; (void)n_in; (void)d_ws; (void)ws_size; (void)out_size;
    rnn_fused<<<BB, 256, 0, stream>>>(
        (const int*)  d_in[0],  (const float*)d_in[1],  (const float*)d_in[2],
        (const float*)d_in[3],  (const float*)d_in[4],  (const float*)d_in[5],
        (const float*)d_in[6],  (const float*)d_in[7],  (const float*)d_in[8],
        (const float*)d_in[9],  (const float*)d_in[10], (const float*)d_in[11],
        (const float*)d_in[12], (float*)d_out);
}

// Round 4
// 515.509 us; speedup vs baseline: 1.1091x; 1.0321x over previous
//
#include <hip/hip_runtime.h>

// T=512, B=512, K=8, V=5, H=30, NL=4, NLAB=3
#define TT 512
#define BB 512
#define KK 8
#define HH 30
#define GG 120   // 4*H
#define NLAYER 4

__device__ __forceinline__ float rcp_f(float x) { return __builtin_amdgcn_rcpf(x); }
__device__ __forceinline__ float rdlane_f(float v, int l) {
    return __int_as_float(__builtin_amdgcn_readlane(__float_as_int(v), l));
}
// packed f32 FMA, broadcast operand in SGPR pair (VOP3P allows one scalar src)
__device__ __forceinline__ float2 pk_fma_s(float2 a, float2 bs, float2 c) {
    float2 d;
    asm("v_pk_fma_f32 %0, %1, %2, %3" : "=v"(d) : "v"(a), "s"(bs), "v"(c));
    return d;
}
__device__ __forceinline__ float2 pk_add(float2 a, float2 b) {
    float2 d;
    asm("v_pk_add_f32 %0, %1, %2" : "=v"(d) : "v"(a), "v"(b));
    return d;
}

// One block = one sample; 4 waves = 4 LSTM layers in an ELASTIC pipeline.
// R3 post-mortem: the per-step __syncthreads phase-locked all waves (stalls
// add instead of overlapping) -> ~2300 cyc/step regardless of instr mix.
// Here waves sync pairwise via an 8-deep LDS h-ring + progress counters,
// checked once per 4-step group. No barrier in the recurrence.
__global__ __launch_bounds__(256, 2) void rnn_fused(
    const int*   __restrict__ xin,  const float* __restrict__ wxin,
    const float* __restrict__ embed,
    const float* __restrict__ Wih,  const float* __restrict__ Whh,
    const float* __restrict__ bih,  const float* __restrict__ bhh,
    const float* __restrict__ W1,   const float* __restrict__ b1,
    const float* __restrict__ W2,   const float* __restrict__ b2,
    const float* __restrict__ fcW,  const float* __restrict__ fcb,
    float* __restrict__ out)
{
    __shared__ alignas(16) float hstore[TT * HH];        // layer-3 h trace
    __shared__ alignas(16) float seqring[2][16][32];     // pooled-embed (wave-0 private)
    __shared__ alignas(16) int   ringx[4][16][KK];       // x stream (wave-0 private)
    __shared__ alignas(16) float ringw[4][16][KK];
    __shared__ alignas(16) float hring[3][8][32];        // layer->layer h ring
    __shared__ alignas(16) float re_s[5 * HH];           // relu(embed)
    __shared__ alignas(16) float energy_s[TT];
    __shared__ float red_s[16];
    __shared__ float part_s[8][HH];
    __shared__ float pooled_s[HH];
    __shared__ float logits_s[3];
    __shared__ int   sync_s[8];                          // [0..3]=prog, [4..7]=cons

    const int tid  = threadIdx.x;
    const int wv   = tid >> 6;
    const int lane = tid & 63;
    const int b    = blockIdx.x;
    volatile int* vs = sync_s;

    // ---- preamble ----
    if (tid < 8) sync_s[tid] = 0;
    if (tid < 5 * HH) re_s[tid] = fmaxf(embed[tid], 0.0f);

    int4 hx = {0,0,0,0}; float4 hw = {0,0,0,0};          // held x/w (wave0, lanes<32)
    if (wv == 0 && lane < 32) {
        const int r = lane >> 1, hf = lane & 1;
        #pragma unroll
        for (int cc = 0; cc < 2; ++cc) {                 // chunks 0,1 -> LDS
            long off = ((long)(16 * cc + r) * BB + b) * KK + hf * 4;
            *(int4*)(&ringx[cc][r][hf * 4])   = *(const int4*)(xin  + off);
            *(float4*)(&ringw[cc][r][hf * 4]) = *(const float4*)(wxin + off);
        }
        long off2 = ((long)(32 + r) * BB + b) * KK + hf * 4;  // chunk 2 -> regs
        hx = *(const int4*)(xin  + off2);
        hw = *(const float4*)(wxin + off2);
    }

    // ---- per-lane LSTM weights (packed float2; rows 120B -> 8B aligned) ----
    const int p  = (lane < 60) ? lane : 59;
    const int g0 = p, g1 = p + 60;   // lanes<30: (i,g); lanes 30-59: (f,o)
    float2 wih0p[15], wih1p[15], whh0p[15], whh1p[15];
    {
        const float* WihL = Wih + wv * GG * HH;
        const float* WhhL = Whh + wv * GG * HH;
        #pragma unroll
        for (int kk = 0; kk < 15; ++kk) {
            wih0p[kk] = *(const float2*)(WihL + g0 * HH + 2 * kk);
            wih1p[kk] = *(const float2*)(WihL + g1 * HH + 2 * kk);
            whh0p[kk] = *(const float2*)(WhhL + g0 * HH + 2 * kk);
            whh1p[kk] = *(const float2*)(WhhL + g1 * HH + 2 * kk);
        }
    }
    const float bias0 = bih[wv * GG + g0] + bhh[wv * GG + g0];
    const float bias1 = bih[wv * GG + g1] + bhh[wv * GG + g1];
    const float mBneg = (lane < HH) ? -2.0f : -1.0f;     // tanh via 2*sig(2x)-1
    const float aB    = (lane < HH) ?  2.0f :  1.0f;
    const float dB    = (lane < HH) ? -1.0f :  0.0f;

    __syncthreads();   // preamble visible (ringx/re_s/sync init)

    float c_val = 0.0f;
    float hprev = 0.0f;

    auto do_step = [&](int t) {
        const float* xsrc = (wv == 0) ? &seqring[(t >> 4) & 1][t & 15][0]
                                      : &hring[wv - 1][t & 7][0];
        const float xi = xsrc[lane & 31];                // 1 ds_read_b32
        float2 ah0 = {0.f,0.f}, ah1 = {0.f,0.f};
        #pragma unroll
        for (int k = 0; k < 15; ++k) {                   // h-side (registers only)
            float2 hp;
            hp.x = rdlane_f(hprev, 2 * k);
            hp.y = rdlane_f(hprev, 2 * k + 1);
            ah0 = pk_fma_s(whh0p[k], hp, ah0);
            ah1 = pk_fma_s(whh1p[k], hp, ah1);
        }
        float2 ax0 = {0.f,0.f}, ax1 = {0.f,0.f};
        #pragma unroll
        for (int k = 0; k < 15; ++k) {                   // x-side
            float2 xp;
            xp.x = rdlane_f(xi, 2 * k);
            xp.y = rdlane_f(xi, 2 * k + 1);
            ax0 = pk_fma_s(wih0p[k], xp, ax0);
            ax1 = pk_fma_s(wih1p[k], xp, ax1);
        }
        const float2 s0 = pk_add(ax0, ah0);
        const float2 s1 = pk_add(ax1, ah1);
        const float gA = s0.x + s0.y + bias0;            // i | f
        const float gB = s1.x + s1.y + bias1;            // g | o
        const float actA = rcp_f(1.0f + __expf(-gA));
        const float sB   = rcp_f(1.0f + __expf(gB * mBneg));
        const float actB = fmaf(aB, sB, dB);
        const float fI = __shfl(actA, lane + HH, 64);
        const float oI = __shfl(actB, lane + HH, 64);
        c_val = fmaf(fI, c_val, actA * actB);            // lanes>=30: garbage, unused
        const float tC = fmaf(2.0f, rcp_f(1.0f + __expf(-2.0f * c_val)), -1.0f);
        const float hv = oI * tC;
        hprev = hv;
        if (lane < HH) {
            if (wv < NLAYER - 1) hring[wv][t & 7][lane] = hv;
            else                 hstore[t * HH + lane]  = hv;
        }
    };

    // ---- elastic pipelined recurrence: 128 groups of 4 steps ----
    for (int T0 = 0; T0 < TT; T0 += 4) {
        if (wv == 0) {
            if ((T0 & 15) == 0) {                        // chunk boundary (private)
                const int c = T0 >> 4;
                if (lane < 32) {
                    const int r = lane >> 1, hf = lane & 1;
                    if (c <= 29) {                       // commit chunk c+2
                        const int sl = (c + 2) & 3;
                        *(int4*)(&ringx[sl][r][hf * 4])   = hx;
                        *(float4*)(&ringw[sl][r][hf * 4]) = hw;
                    }
                    if (c <= 28) {                       // load chunk c+3
                        long off = ((long)(16 * (c + 3) + r) * BB + b) * KK + hf * 4;
                        hx = *(const int4*)(xin  + off);
                        hw = *(const float4*)(wxin + off);
                    }
                }
                const int sl = c & 3, par = c & 1;       // gather pooled chunk c
                #pragma unroll
                for (int rr = 0; rr < 8; ++rr) {
                    const int o = lane + rr * 64;
                    if (o < 480) {
                        const int tr = o / HH, j = o - tr * HH;
                        int4   xa = *(const int4*)(&ringx[sl][tr][0]);
                        int4   xb = *(const int4*)(&ringx[sl][tr][4]);
                        float4 wa = *(const float4*)(&ringw[sl][tr][0]);
                        float4 wb = *(const float4*)(&ringw[sl][tr][4]);
                        float acc = re_s[xa.x * HH + j] * wa.x;
                        acc = fmaf(re_s[xa.y * HH + j], wa.y, acc);
                        acc = fmaf(re_s[xa.z * HH + j], wa.z, acc);
                        acc = fmaf(re_s[xa.w * HH + j], wa.w, acc);
                        acc = fmaf(re_s[xb.x * HH + j], wb.x, acc);
                        acc = fmaf(re_s[xb.y * HH + j], wb.y, acc);
                        acc = fmaf(re_s[xb.z * HH + j], wb.z, acc);
                        acc = fmaf(re_s[xb.w * HH + j], wb.w, acc);
                        seqring[par][tr][j] = acc * 0.125f;
                    }
                }
                __threadfence_block();                   // gather visible to own reads
            }
        } else {
            while (vs[wv - 1] < T0 + 4) __builtin_amdgcn_s_sleep(2);   // x ready
        }
        if (wv < NLAYER - 1) {
            while (vs[4 + wv + 1] < T0 - 4) __builtin_amdgcn_s_sleep(2); // ring free
        }
        __threadfence_block();                           // order spins vs ring reads
        do_step(T0 + 0);
        do_step(T0 + 1);
        do_step(T0 + 2);
        do_step(T0 + 3);
        __threadfence_block();                           // drain h writes
        if (lane == 0) {
            if (wv < NLAYER - 1) vs[wv]     = T0 + 4;    // producer progress
            if (wv > 0)          vs[4 + wv] = T0 + 4;    // consumer progress
        }
    }

    __syncthreads();   // hstore complete

    // ---- attention, t-per-lane: e_t = relu(h_t @ W1 + b1) @ W2 + b2 ----
    {
        float w1cx[15], w1cy[15];                        // W1 column `lane`
        #pragma unroll
        for (int k = 0; k < 15; ++k) {
            w1cx[k] = W1[(2 * k) * 64 + lane];
            w1cy[k] = W1[(2 * k + 1) * 64 + lane];
        }
        const float b1v = b1[lane];
        const float w2v = W2[lane];
        const float b2v = b2[0];
        #pragma unroll
        for (int pass = 0; pass < 2; ++pass) {
            const int t = wv * 128 + pass * 64 + lane;   // each lane owns one t
            float2 h2[15];
            #pragma unroll
            for (int k = 0; k < 15; ++k)
                h2[k] = *(const float2*)(hstore + t * HH + 2 * k);
            float e = b2v;
            for (int u = 0; u < 64; ++u) {               // W1 broadcast via readlane
                float2 acc = {0.f, 0.f};
                #pragma unroll
                for (int k = 0; k < 15; ++k) {
                    float2 wp;
                    wp.x = rdlane_f(w1cx[k], u);
                    wp.y = rdlane_f(w1cy[k], u);
                    acc = pk_fma_s(h2[k], wp, acc);
                }
                const float su = acc.x + acc.y + rdlane_f(b1v, u);
                e = fmaf(fmaxf(su, 0.0f), rdlane_f(w2v, u), e);
            }
            energy_s[t] = e;
        }
    }
    __syncthreads();

    // ---- softmax over T ----
    float mx = -3.0e38f;
    for (int i = tid; i < TT; i += 256) mx = fmaxf(mx, energy_s[i]);
    #pragma unroll
    for (int m = 1; m < 64; m <<= 1) mx = fmaxf(mx, __shfl_xor(mx, m, 64));
    if (lane == 0) red_s[wv] = mx;
    __syncthreads();
    mx = fmaxf(fmaxf(red_s[0], red_s[1]), fmaxf(red_s[2], red_s[3]));
    float ssum = 0.0f;
    for (int i = tid; i < TT; i += 256) {
        float ev = __expf(energy_s[i] - mx);
        energy_s[i] = ev;
        ssum += ev;
    }
    #pragma unroll
    for (int m = 1; m < 64; m <<= 1) ssum += __shfl_xor(ssum, m, 64);
    if (lane == 0) red_s[8 + wv] = ssum;
    __syncthreads();
    const float invS = rcp_f(red_s[8] + red_s[9] + red_s[10] + red_s[11]);

    // ---- pooled_j = sum_t softmax_t * h[t][j] ----
    {
        const int g = tid >> 5, jj = tid & 31;
        if (jj < HH) {
            float part = 0.0f;
            for (int t = g; t < TT; t += 8)
                part = fmaf(energy_s[t] * invS, hstore[t * HH + jj], part);
            part_s[g][jj] = part;
        }
    }
    __syncthreads();
    if (tid < HH) {
        float pv = 0.0f;
        #pragma unroll
        for (int q = 0; q < 8; ++q) pv += part_s[q][tid];
        pooled_s[tid] = pv;
    }
    __syncthreads();

    // ---- FC (30->3) + softmax ----
    if (tid < 3) {
        float acc = fcb[tid];
        #pragma unroll
        for (int k = 0; k < HH; ++k) acc = fmaf(pooled_s[k], fcW[k * 3 + tid], acc);
        logits_s[tid] = acc;
    }
    __syncthreads();
    if (tid == 0) {
        float l0 = logits_s[0], l1 = logits_s[1], l2 = logits_s[2];
        float m3 = fmaxf(l0, fmaxf(l1, l2));
        float e0 = __expf(l0 - m3), e1 = __expf(l1 - m3), e2 = __expf(l2 - m3);
        float inv = rcp_f(e0 + e1 + e2);
        out[b * 3 + 0] = e0 * inv; out[b * 3 + 1] = e1 * inv; out[b * 3 + 2] = e2 * inv;
    }
}

extern "C" void kernel_launch(void* const* d_in, const int* in_sizes, int n_in,
                              void* d_out, int out_size, void* d_ws, size_t ws_size,
                              hipStream_t stream)
{
    (void)in_sizes; (void)n_in; (void)d_ws; (void)ws_size; (void)out_size;
    rnn_fused<<<BB, 256, 0, stream>>>(
        (const int*)  d_in[0],  (const float*)d_in[1],  (const float*)d_in[2],
        (const float*)d_in[3],  (const float*)d_in[4],  (const float*)d_in[5],
        (const float*)d_in[6],  (const float*)d_in[7],  (const float*)d_in[8],
        (const float*)d_in[9],  (const float*)d_in[10], (const float*)d_in[11],
        (const float*)d_in[12], (float*)d_out);
}